// Round 2
// baseline (658.557 us; speedup 1.0000x reference)
//
#include <hip/hip_runtime.h>
#include <cfloat>

#define DIM_IN 256
#define HIDDEN 32
#define NE 64

// One thread per token. Weights live in LDS; all lanes of a wave read the
// same weight element (broadcast, conflict-free) while each lane streams its
// own x row. h[32] and z[64] are register arrays — every access uses
// compile-time indices (full unroll) so nothing spills to scratch.
__launch_bounds__(256, 3)
__global__ void router_fwd(const float* __restrict__ x,
                           const float* __restrict__ W1,
                           const float* __restrict__ b1,
                           const float* __restrict__ W2,
                           const float* __restrict__ b2,
                           float* __restrict__ out,
                           int n_tokens) {
  __shared__ __align__(16) float sW1[DIM_IN * HIDDEN];  // 32 KB
  __shared__ __align__(16) float sW2[HIDDEN * NE];      // 8 KB
  __shared__ float sb1[HIDDEN];
  __shared__ float sb2[NE];

  // --- stage weights (once per block, float4-coalesced) ---
  {
    const float4* W1v = reinterpret_cast<const float4*>(W1);
    float4* sW1v = reinterpret_cast<float4*>(sW1);
    for (int i = threadIdx.x; i < DIM_IN * HIDDEN / 4; i += blockDim.x) sW1v[i] = W1v[i];
    const float4* W2v = reinterpret_cast<const float4*>(W2);
    float4* sW2v = reinterpret_cast<float4*>(sW2);
    for (int i = threadIdx.x; i < HIDDEN * NE / 4; i += blockDim.x) sW2v[i] = W2v[i];
    if (threadIdx.x < HIDDEN) sb1[threadIdx.x] = b1[threadIdx.x];
    if (threadIdx.x < NE)     sb2[threadIdx.x] = b2[threadIdx.x];
  }
  __syncthreads();

  const int t = blockIdx.x * blockDim.x + threadIdx.x;
  if (t >= n_tokens) return;

  const float4* xr = reinterpret_cast<const float4*>(x + (size_t)t * DIM_IN);

  // --- layer 1: h = x @ W1 (bias+tanh after, matching np op order) ---
  float h[HIDDEN];
#pragma unroll
  for (int j = 0; j < HIDDEN; ++j) h[j] = 0.0f;

  for (int i0 = 0; i0 < DIM_IN; i0 += 8) {  // 32 iterations, body ~1.5 KB
    const float4 xa = xr[i0 / 4];
    const float4 xb = xr[i0 / 4 + 1];
    const float xs[8] = {xa.x, xa.y, xa.z, xa.w, xb.x, xb.y, xb.z, xb.w};
#pragma unroll
    for (int k = 0; k < 8; ++k) {
      const float xv = xs[k];
      const float4* wrow = reinterpret_cast<const float4*>(sW1 + (i0 + k) * HIDDEN);
#pragma unroll
      for (int j4 = 0; j4 < HIDDEN / 4; ++j4) {
        const float4 w = wrow[j4];  // wave-uniform ds_read_b128 (broadcast)
        h[4 * j4 + 0] = fmaf(xv, w.x, h[4 * j4 + 0]);
        h[4 * j4 + 1] = fmaf(xv, w.y, h[4 * j4 + 1]);
        h[4 * j4 + 2] = fmaf(xv, w.z, h[4 * j4 + 2]);
        h[4 * j4 + 3] = fmaf(xv, w.w, h[4 * j4 + 3]);
      }
    }
  }

  // bias + tanh.  tanh(v) = 1 - 2/(e^{2v}+1): no inf/inf NaN, ~2 ulp.
#pragma unroll
  for (int j = 0; j < HIDDEN; ++j) {
    const float v = h[j] + sb1[j];
    const float e = __expf(2.0f * v);
    h[j] = 1.0f - 2.0f / (e + 1.0f);
  }

  // --- layer 2: z = (h @ W2 + b2) / TEMP --- (j fully unrolled: static idx)
  float z[NE];
#pragma unroll
  for (int e = 0; e < NE; ++e) z[e] = 0.0f;
#pragma unroll
  for (int j = 0; j < HIDDEN; ++j) {
    const float hv = h[j];
    const float4* wrow = reinterpret_cast<const float4*>(sW2 + j * NE);
#pragma unroll
    for (int e4 = 0; e4 < NE / 4; ++e4) {
      const float4 w = wrow[e4];
      z[4 * e4 + 0] = fmaf(hv, w.x, z[4 * e4 + 0]);
      z[4 * e4 + 1] = fmaf(hv, w.y, z[4 * e4 + 1]);
      z[4 * e4 + 2] = fmaf(hv, w.z, z[4 * e4 + 2]);
      z[4 * e4 + 3] = fmaf(hv, w.w, z[4 * e4 + 3]);
    }
  }
#pragma unroll
  for (int e = 0; e < NE; ++e) z[e] = (z[e] + sb2[e]) * 10.0f;

  // --- top-2 on scaled logits: strict '>' ascending => ties pick lower
  // index, matching jax.lax.top_k.  m (softmax max) == v1.
  float v1 = -FLT_MAX, v2 = -FLT_MAX;
  int i1 = 0, i2 = 0;
#pragma unroll
  for (int e = 0; e < NE; ++e) {
    const float v = z[e];
    const bool g1 = v > v1;
    const bool g2 = v > v2;
    v2 = g1 ? v1 : (g2 ? v : v2);
    i2 = g1 ? i1 : (g2 ? e : i2);
    v1 = g1 ? v : v1;
    i1 = g1 ? e : i1;
  }

  // softmax denominator with max subtraction (exp(0)=1 at argmax, like ref)
  float S = 0.0f;
#pragma unroll
  for (int e = 0; e < NE; ++e) S += __expf(z[e] - v1);

  const float pa = 1.0f / S;               // p_soft[top1]
  const float pb = __expf(v2 - v1) / S;    // p_soft[top2]
  const float denom = (pa + pb) + 1e-9f;   // p_hard renorm, ref formula
  const float oa = pa / denom;
  const float ob = pb / denom;

  // --- write row: zeros except the two selected experts ---
  float* orow = out + (size_t)t * NE;
#pragma unroll
  for (int e4 = 0; e4 < NE / 4; ++e4) {
    float4 v;
    const int b0 = 4 * e4;
    v.x = (b0 + 0 == i1) ? oa : ((b0 + 0 == i2) ? ob : 0.0f);
    v.y = (b0 + 1 == i1) ? oa : ((b0 + 1 == i2) ? ob : 0.0f);
    v.z = (b0 + 2 == i1) ? oa : ((b0 + 2 == i2) ? ob : 0.0f);
    v.w = (b0 + 3 == i1) ? oa : ((b0 + 3 == i2) ? ob : 0.0f);
    reinterpret_cast<float4*>(orow)[e4] = v;
  }
}

extern "C" void kernel_launch(void* const* d_in, const int* in_sizes, int n_in,
                              void* d_out, int out_size, void* d_ws, size_t ws_size,
                              hipStream_t stream) {
  const float* x  = (const float*)d_in[0];
  const float* W1 = (const float*)d_in[1];
  const float* b1 = (const float*)d_in[2];
  const float* W2 = (const float*)d_in[3];
  const float* b2 = (const float*)d_in[4];
  float* out = (float*)d_out;
  const int n_tokens = in_sizes[0] / DIM_IN;
  const int block = 256;
  const int grid = (n_tokens + block - 1) / block;
  hipLaunchKernelGGL(router_fwd, dim3(grid), dim3(block), 0, stream,
                     x, W1, b1, W2, b2, out, n_tokens);
}

// Round 3
// 378.435 us; speedup vs baseline: 1.7402x; 1.7402x over previous
//
#include <hip/hip_runtime.h>
#include <cfloat>

#define DIM_IN 256
#define HIDDEN 32
#define NE 64
#define ECH 16
#define BLOCK 256

// One thread per token. Weights are read with wave-uniform indices from
// __restrict__ const global pointers -> compiler emits s_load (scalar cache,
// scalar pipe), so the DS pipe is free and VALU does only FMAs.
// LDS is used only for an output transpose so HBM writes are full 64B lines.
// All register arrays are indexed with compile-time constants (full unroll).
__launch_bounds__(BLOCK, 4)
__global__ void router_fwd(const float* __restrict__ x,
                           const float* __restrict__ W1,
                           const float* __restrict__ b1,
                           const float* __restrict__ W2,
                           const float* __restrict__ b2,
                           float* __restrict__ out, int n) {
  __shared__ float obuf[BLOCK][ECH + 1];  // +1 pad: conflict-free transpose
  const int tid = threadIdx.x;
  const int t   = blockIdx.x * BLOCK + tid;
  const bool active = t < n;

  const float4* __restrict__ xr =
      reinterpret_cast<const float4*>(x + (size_t)(active ? t : 0) * DIM_IN);

  // --- layer 1: h = x @ W1 (bias+tanh after; np op order) ---
  float h[HIDDEN];
#pragma unroll
  for (int j = 0; j < HIDDEN; ++j) h[j] = 0.0f;

#pragma unroll 1
  for (int i0 = 0; i0 < DIM_IN; i0 += 16) {  // 64B of x per lane per iter
    const float4 x0 = xr[(i0 >> 2) + 0];
    const float4 x1 = xr[(i0 >> 2) + 1];
    const float4 x2 = xr[(i0 >> 2) + 2];
    const float4 x3 = xr[(i0 >> 2) + 3];
    const float xs[16] = {x0.x, x0.y, x0.z, x0.w, x1.x, x1.y, x1.z, x1.w,
                          x2.x, x2.y, x2.z, x2.w, x3.x, x3.y, x3.z, x3.w};
#pragma unroll
    for (int k = 0; k < 16; ++k) {
      const float* __restrict__ wrow = W1 + (i0 + k) * HIDDEN;  // uniform
      const float xv = xs[k];
#pragma unroll
      for (int j = 0; j < HIDDEN; ++j) h[j] = fmaf(xv, wrow[j], h[j]);
    }
  }

  // bias + tanh.  tanh(v) = 1 - 2/(e^{2v}+1): no inf/inf NaN.
#pragma unroll
  for (int j = 0; j < HIDDEN; ++j) {
    const float v = h[j] + b1[j];  // b1: uniform -> s_load
    const float e = __expf(2.0f * v);
    h[j] = 1.0f - 2.0f / (e + 1.0f);
  }

  // --- layer 2 in 16-expert chunks + online top-2 / exp-sum ---
  float v1 = -FLT_MAX, v2 = -FLT_MAX, S = 0.0f;
  int   i1 = 0, i2 = 0;

#pragma unroll 1
  for (int c = 0; c < NE / ECH; ++c) {
    float zc[ECH];
#pragma unroll
    for (int e = 0; e < ECH; ++e) zc[e] = 0.0f;
#pragma unroll
    for (int j = 0; j < HIDDEN; ++j) {
      const float hv = h[j];
      const float* __restrict__ wrow = W2 + j * NE + c * ECH;  // uniform
#pragma unroll
      for (int e = 0; e < ECH; ++e) zc[e] = fmaf(hv, wrow[e], zc[e]);
    }
    const float m_prev = v1;
    // top-2: strict '>' ascending scan => ties pick lower index (lax.top_k)
#pragma unroll
    for (int e = 0; e < ECH; ++e) {
      const float v = (zc[e] + b2[c * ECH + e]) * 10.0f;  // /TEMP
      zc[e] = v;
      const int ge = c * ECH + e;
      const bool g1 = v > v1;
      const bool g2 = v > v2;
      v2 = g1 ? v1 : (g2 ? v : v2);
      i2 = g1 ? i1 : (g2 ? ge : i2);
      v1 = g1 ? v : v1;
      i1 = g1 ? ge : i1;
    }
    S *= __expf(m_prev - v1);  // rescale old sum to new max (chunk 0: 0*0=0)
#pragma unroll
    for (int e = 0; e < ECH; ++e) S += __expf(zc[e] - v1);
  }

  const float pa = 1.0f / S;             // p_soft[top1] (exp(0)=1)
  const float pb = __expf(v2 - v1) / S;  // p_soft[top2]
  const float d  = pa + pb + 1e-9f;      // ref renorm formula
  const float oa = active ? pa / d : 0.0f;
  const float ob = active ? pb / d : 0.0f;

  // --- output: LDS transpose so HBM writes are full 64B lines ---
  const long obase = (long)blockIdx.x * BLOCK;
#pragma unroll 1
  for (int c = 0; c < NE / ECH; ++c) {
    __syncthreads();  // previous chunk's readers done before overwrite
#pragma unroll
    for (int e = 0; e < ECH; ++e) {
      const int ge = c * ECH + e;
      obuf[tid][e] = (ge == i1) ? oa : ((ge == i2) ? ob : 0.0f);
    }
    __syncthreads();
#pragma unroll
    for (int m = 0; m < 4; ++m) {
      const int f = m * BLOCK + tid;   // consecutive lanes -> consecutive 16B
      const int tok = f >> 2, part = f & 3;
      if (obase + tok < n) {
        float4 v;
        v.x = obuf[tok][part * 4 + 0];
        v.y = obuf[tok][part * 4 + 1];
        v.z = obuf[tok][part * 4 + 2];
        v.w = obuf[tok][part * 4 + 3];
        reinterpret_cast<float4*>(out + (obase + tok) * (long)NE + c * ECH)[part] = v;
      }
    }
  }
}

extern "C" void kernel_launch(void* const* d_in, const int* in_sizes, int n_in,
                              void* d_out, int out_size, void* d_ws, size_t ws_size,
                              hipStream_t stream) {
  const float* x  = (const float*)d_in[0];
  const float* W1 = (const float*)d_in[1];
  const float* b1 = (const float*)d_in[2];
  const float* W2 = (const float*)d_in[3];
  const float* b2 = (const float*)d_in[4];
  float* out = (float*)d_out;
  const int n_tokens = in_sizes[0] / DIM_IN;
  const int grid = (n_tokens + BLOCK - 1) / BLOCK;
  hipLaunchKernelGGL(router_fwd, dim3(grid), dim3(BLOCK), 0, stream,
                     x, W1, b1, W2, b2, out, n_tokens);
}